// Round 2
// baseline (101.938 us; speedup 1.0000x reference)
//
#include <hip/hip_runtime.h>

#define TPB   128
#define LSEQ  1024          // L
#define NCOL  1022          // n = L-2
#define NROW  1021          // n-1 rows of the cumprod
#define CBLK  4             // column blocks per (b,d): 4*128 slots >= 511

typedef float v2f __attribute__((ext_vector_type(2)));   // native vec2 for NT store

// One thread owns TWO adjacent output columns (j0, j0+1) of one (batch, dir)
// matrix and walks the serial cumprod down all 1021 rows, storing 8B/row.
// p(r,j) = clamp((v - s[j])*10 + 1, 0, 1), v = s[j-1-r] (0 if index < 0).
// Backward-walk register reuse: v_hi(r+1) == v_lo(r) -> 1 LDS read / iter.
__global__ __launch_bounds__(TPB) void gate_kernel(
    const float* __restrict__ score,
    const int*   __restrict__ score_idx,
    float*       __restrict__ out)
{
    __shared__ float s[NCOL];

    const int bid = blockIdx.x;
    const int cb  = bid & (CBLK - 1);   // column-block 0..3
    const int bd  = bid >> 2;           // b*2 + d
    const int d   = bd & 1;
    const int b   = bd >> 1;
    const int tid = threadIdx.x;

    // Stage direction-applied s into LDS (honor the score_idx gather).
    const int* idxRow = score_idx + b * LSEQ + 1;   // docs[b][1: ]
    for (int i = tid; i < NCOL; i += TPB) {
        int src = (d == 0) ? i : (NCOL - 1 - i);
        s[i] = score[idxRow[src]];
    }
    __syncthreads();

    const int slot = cb * TPB + tid;     // float2 column slot
    if (slot >= NCOL / 2) return;        // 511 valid slots
    const int j0 = slot * 2;

    const float sj0 = s[j0];
    const float sj1 = s[j0 + 1];
    const float c0  = 1.0f - 10.0f * sj0;
    const float c1  = 1.0f - 10.0f * sj1;

    float a0 = 1.0f, a1 = 1.0f;
    float vhi = sj0;          // v for column j0+1 at r=0 is s[j0]
    int   k   = j0 - 1;       // fresh load index (column j0's v at r=0)

    float* outp = out + (size_t)bd * NROW * NCOL + j0;

    for (int r = 0; r < NROW; ++r) {
        float vlo = (k >= 0) ? s[k] : 0.0f;

        float p0 = __builtin_fmaf(vlo, 10.0f, c0);
        float p1 = __builtin_fmaf(vhi, 10.0f, c1);
        p0 = fminf(fmaxf(p0, 0.0f), 1.0f);   // v_med3 clamp
        p1 = fminf(fmaxf(p1, 0.0f), 1.0f);

        a0 *= p0;
        a1 *= p1;

        v2f w; w.x = a0; w.y = a1;
        __builtin_nontemporal_store(w, (v2f*)outp);

        outp += NCOL;
        vhi = vlo;
        --k;
    }
}

extern "C" void kernel_launch(void* const* d_in, const int* in_sizes, int n_in,
                              void* d_out, int out_size, void* d_ws, size_t ws_size,
                              hipStream_t stream)
{
    const float* score = (const float*)d_in[0];
    const int*   sidx  = (const int*)d_in[1];
    float*       out   = (float*)d_out;

    const int B = in_sizes[0] / LSEQ;          // 32
    dim3 grid(B * 2 * CBLK), block(TPB);
    gate_kernel<<<grid, block, 0, stream>>>(score, sidx, out);
}